// Round 1
// baseline (280.066 us; speedup 1.0000x reference)
//
#include <hip/hip_runtime.h>

// Masked self-attention, B=4 T=2048 C=1024, single head (head dim = C).
// Pipeline (all bf16 MFMA GEMMs, m97-style 128x128 tile, global_load_lds):
//   1. cvt: x, Wq/Wk/Wv/Wo fp32 -> bf16 in ws; biases copied contiguous.
//   2. gemm (z=0,1): Q = xWq^T+bq, K = xWk^T+bk          (bf16 out)
//      gemm (trans): Vt[b][c][t] = (xWv^T+bv)^T          (bf16 out)
//   3. gemm (skip-upper): S = Q K^T * 1/32               (bf16 out)
//   4. softmax_causal in-place: S -> P (zeros above diag)
//   5. gemm (k-clamp): attn = P @ V  (B-operand = Vt)    (bf16, reuses xb slot)
//   6. gemm (f32 out): out = attn Wo^T + bo
// Workspace peak ~104 MiB.

typedef __attribute__((ext_vector_type(8))) short short8;
typedef __attribute__((ext_vector_type(4))) float f32x4;
typedef __attribute__((ext_vector_type(4))) unsigned short us4;
typedef __attribute__((ext_vector_type(8))) unsigned short us8;
typedef __attribute__((ext_vector_type(4))) float fl4;

__device__ __forceinline__ unsigned short f2b(float f) {
  unsigned int u = __builtin_bit_cast(unsigned int, f);
  u += 0x7fffu + ((u >> 16) & 1u);   // round-to-nearest-even
  return (unsigned short)(u >> 16);
}
__device__ __forceinline__ float b2f(unsigned short h) {
  unsigned int u = ((unsigned int)h) << 16;
  return __builtin_bit_cast(float, u);
}

// ---------------- fp32 -> bf16 convert (vectorized) ----------------
__global__ __launch_bounds__(256) void cvt_kernel(const float* __restrict__ src,
                                                  unsigned short* __restrict__ dst,
                                                  int n4) {
  int i = blockIdx.x * blockDim.x + threadIdx.x;
  if (i < n4) {
    fl4 f = *(const fl4*)&src[(size_t)i << 2];
    us4 o;
#pragma unroll
    for (int j = 0; j < 4; ++j) o[j] = f2b(f[j]);
    *(us4*)&dst[(size_t)i << 2] = o;
  }
}

__global__ __launch_bounds__(256) void bias_copy(const float* bq, const float* bk,
                                                 const float* bv, const float* bo,
                                                 float* dst) {
  int i = blockIdx.x * 256 + threadIdx.x;   // grid 16 -> 4096
  int sel = i >> 10, idx = i & 1023;
  const float* p = sel == 0 ? bq : sel == 1 ? bk : sel == 2 ? bv : bo;
  dst[i] = p[idx];
}

// ---------------- B^T GEMM: C[m][n] = sum_k A[m][k]*B[n][k] ----------------
// A, B bf16 (k contiguous, ld = K). 128x128 tile, BK=32, 4 waves (2x2 of 64x64).
template<bool TRANS_OUT, bool OUT_F32, bool CLAMP_K, bool SKIP_UPPER>
__global__ __launch_bounds__(256)
void gemm_bt(const unsigned short* __restrict__ A,
             const unsigned short* __restrict__ B,
             void* __restrict__ Cout,
             const float* __restrict__ bias, long long sBiasZ,
             float scale, int M, int N, int K,
             long long sAz, long long sBz, long long sCz)
{
  const int m0 = blockIdx.y << 7;
  const int n0 = blockIdx.x << 7;
  if (SKIP_UPPER && n0 > m0 + 127) return;   // fully-masked score block
  const int z = blockIdx.z;

  __shared__ unsigned short lA[128 * 32];
  __shared__ unsigned short lB[128 * 32];

  const unsigned short* Ab = A + (size_t)z * sAz;
  const unsigned short* Bb = B + (size_t)z * sBz;

  const int tid  = threadIdx.x;
  const int lane = tid & 63;
  const int wid  = tid >> 6;
  const int wm   = wid >> 1;
  const int wn   = wid & 1;
  const int fr   = lane & 15;   // row (A) / col (B) within 16
  const int kg   = lane >> 4;   // k-group

  int kEnd = K;
  if (CLAMP_K) kEnd = (m0 + 128 < K) ? (m0 + 128) : K;   // causal PV clamp

  f32x4 acc[4][4];
#pragma unroll
  for (int i = 0; i < 4; ++i)
#pragma unroll
    for (int j = 0; j < 4; ++j)
      acc[i][j] = f32x4{0.f, 0.f, 0.f, 0.f};

  // staging: wave w owns rows [32w,32w+32); one gll call = 64 lanes x 16B = 1KB
  const int srow = (wid << 5) + (lane >> 2);
  const int scol = (lane & 3) << 3;
  const unsigned short* gA0 = Ab + (size_t)(m0 + srow) * K + scol;
  const unsigned short* gB0 = Bb + (size_t)(n0 + srow) * K + scol;
  unsigned short* lAw = &lA[wid << 10];
  unsigned short* lBw = &lB[wid << 10];

  for (int k0 = 0; k0 < kEnd; k0 += 32) {
    __syncthreads();   // previous iter's ds_reads done before overwrite
#pragma unroll
    for (int c = 0; c < 2; ++c) {
      __builtin_amdgcn_global_load_lds(
          (const __attribute__((address_space(1))) void*)(gA0 + (size_t)(c << 4) * K + k0),
          (__attribute__((address_space(3))) void*)(lAw + (c << 9)), 16, 0, 0);
      __builtin_amdgcn_global_load_lds(
          (const __attribute__((address_space(1))) void*)(gB0 + (size_t)(c << 4) * K + k0),
          (__attribute__((address_space(3))) void*)(lBw + (c << 9)), 16, 0, 0);
    }
    __syncthreads();   // compiler drains vmcnt(0) before barrier

    short8 af[4], bfr[4];
#pragma unroll
    for (int i = 0; i < 4; ++i) {
      af[i]  = *(const short8*)&lA[(((wm << 6) + (i << 4) + fr) << 5) + (kg << 3)];
      bfr[i] = *(const short8*)&lB[(((wn << 6) + (i << 4) + fr) << 5) + (kg << 3)];
    }
#pragma unroll
    for (int i = 0; i < 4; ++i)
#pragma unroll
      for (int j = 0; j < 4; ++j)
        acc[i][j] = __builtin_amdgcn_mfma_f32_16x16x32_bf16(af[i], bfr[j], acc[i][j], 0, 0, 0);
  }

  const float* biasz = bias ? (bias + (size_t)z * sBiasZ) : nullptr;

  if (TRANS_OUT) {
    // write C^T: Vt[b][c][t], per-batch [N][2048]; 128-row blocks never straddle b
    const int batch = m0 >> 11;
    const int tbase = (m0 & 2047) + (wm << 6) + (kg << 2);
    unsigned short* Cb = (unsigned short*)Cout + (size_t)batch * N * 2048;
#pragma unroll
    for (int j = 0; j < 4; ++j) {
      const int c = n0 + (wn << 6) + (j << 4) + fr;
      const float bv = biasz ? biasz[c] : 0.f;
#pragma unroll
      for (int i = 0; i < 4; ++i) {
        const int t = tbase + (i << 4);
        us4 v;
#pragma unroll
        for (int jj = 0; jj < 4; ++jj) v[jj] = f2b(acc[i][j][jj] * scale + bv);
        *(us4*)&Cb[(size_t)c * 2048 + t] = v;
      }
    }
  } else {
    float* Cf = (float*)Cout + (size_t)z * sCz;
    unsigned short* Ch = (unsigned short*)Cout + (size_t)z * sCz;
#pragma unroll
    for (int j = 0; j < 4; ++j) {
      const int c = n0 + (wn << 6) + (j << 4) + fr;
      const float bv = biasz ? biasz[c] : 0.f;
#pragma unroll
      for (int i = 0; i < 4; ++i) {
        const int r0 = m0 + (wm << 6) + (i << 4) + (kg << 2);
#pragma unroll
        for (int jj = 0; jj < 4; ++jj) {
          const float v = acc[i][j][jj] * scale + bv;
          if (OUT_F32) Cf[(size_t)(r0 + jj) * N + c] = v;
          else         Ch[(size_t)(r0 + jj) * N + c] = f2b(v);
        }
      }
    }
  }
}

// ---------------- causal softmax, in-place over bf16 rows ----------------
__global__ __launch_bounds__(256)
void softmax_causal(unsigned short* __restrict__ S, int T) {
  const int t = blockIdx.x, b = blockIdx.y;
  unsigned short* row = S + ((size_t)b * T + t) * T;
  const int tid  = threadIdx.x;
  const int lane = tid & 63;
  const int wid  = tid >> 6;
  const int base = tid << 3;   // 256 threads * 8 = 2048

  us8 raw = *(const us8*)&row[base];
  float v[8];
  float mx = -3.0e38f;
#pragma unroll
  for (int j = 0; j < 8; ++j) {
    const int s = base + j;
    v[j] = (s <= t) ? b2f(raw[j]) : -3.0e38f;
    mx = fmaxf(mx, v[j]);
  }
#pragma unroll
  for (int m = 32; m; m >>= 1) mx = fmaxf(mx, __shfl_xor(mx, m, 64));
  __shared__ float red[4];
  if (lane == 0) red[wid] = mx;
  __syncthreads();
  mx = fmaxf(fmaxf(red[0], red[1]), fmaxf(red[2], red[3]));

  float e[8];
  float sum = 0.f;
#pragma unroll
  for (int j = 0; j < 8; ++j) { e[j] = __expf(v[j] - mx); sum += e[j]; }
#pragma unroll
  for (int m = 32; m; m >>= 1) sum += __shfl_xor(sum, m, 64);
  __syncthreads();                // everyone done reading red (max phase)
  if (lane == 0) red[wid] = sum;
  __syncthreads();
  sum = red[0] + red[1] + red[2] + red[3];
  const float inv = 1.f / sum;

  us8 o;
#pragma unroll
  for (int j = 0; j < 8; ++j) o[j] = f2b(e[j] * inv);
  *(us8*)&row[base] = o;
}

// ---------------- host-side launch ----------------
extern "C" void kernel_launch(void* const* d_in, const int* in_sizes, int n_in,
                              void* d_out, int out_size, void* d_ws, size_t ws_size,
                              hipStream_t stream) {
  (void)in_sizes; (void)n_in; (void)out_size; (void)ws_size;
  const float* x  = (const float*)d_in[0];
  const float* Wq = (const float*)d_in[1];
  const float* bq = (const float*)d_in[2];
  const float* Wk = (const float*)d_in[3];
  const float* bk = (const float*)d_in[4];
  const float* Wv = (const float*)d_in[5];
  const float* bv = (const float*)d_in[6];
  const float* Wo = (const float*)d_in[7];
  const float* bo = (const float*)d_in[8];

  const int B = 4, T = 2048, C = 1024;
  const int M = B * T;                 // 8192

  unsigned short* xb   = (unsigned short*)d_ws;          // M*C
  unsigned short* Wqb  = xb  + (size_t)M * C;            // C*C each
  unsigned short* Wkb  = Wqb + (size_t)C * C;
  unsigned short* Wvb  = Wkb + (size_t)C * C;
  unsigned short* Wob  = Wvb + (size_t)C * C;
  unsigned short* Q    = Wob + (size_t)C * C;            // M*C
  unsigned short* Kb   = Q   + (size_t)M * C;            // M*C
  unsigned short* Vt   = Kb  + (size_t)M * C;            // M*C   [b][c][t]
  unsigned short* S    = Vt  + (size_t)M * C;            // B*T*T (becomes P)
  float*          bws  = (float*)(S + (size_t)B * T * T);// 4*C fp32
  unsigned short* attn = xb;                             // reuse xb slot

  // 1. converts
  cvt_kernel<<<(M * C / 4 + 255) / 256, 256, 0, stream>>>(x, xb, M * C / 4);
  cvt_kernel<<<(C * C / 4 + 255) / 256, 256, 0, stream>>>(Wq, Wqb, C * C / 4);
  cvt_kernel<<<(C * C / 4 + 255) / 256, 256, 0, stream>>>(Wk, Wkb, C * C / 4);
  cvt_kernel<<<(C * C / 4 + 255) / 256, 256, 0, stream>>>(Wv, Wvb, C * C / 4);
  cvt_kernel<<<(C * C / 4 + 255) / 256, 256, 0, stream>>>(Wo, Wob, C * C / 4);
  bias_copy<<<16, 256, 0, stream>>>(bq, bk, bv, bo, bws);

  // 2. Q and K projections (z=0 -> Q, z=1 -> K; Wqb/Wkb and Q/Kb contiguous)
  gemm_bt<false, false, false, false><<<dim3(C / 128, M / 128, 2), 256, 0, stream>>>(
      xb, Wqb, Q, bws, (long long)C, 1.f, M, C, C,
      0LL, (long long)C * C, (long long)M * C);
  // V projection, stored transposed
  gemm_bt<true, false, false, false><<<dim3(C / 128, M / 128, 1), 256, 0, stream>>>(
      xb, Wvb, Vt, bws + 2 * C, 0LL, 1.f, M, C, C, 0LL, 0LL, 0LL);

  // 3. scores: S = Q K^T / sqrt(C)  (bf16), skip fully-masked blocks
  gemm_bt<false, false, false, true><<<dim3(T / 128, T / 128, B), 256, 0, stream>>>(
      Q, Kb, S, nullptr, 0LL, 0.03125f, T, T, C,
      (long long)T * C, (long long)T * C, (long long)T * T);

  // 4. causal softmax in-place (writes zeros above diagonal)
  softmax_causal<<<dim3(T, B), 256, 0, stream>>>(S, T);

  // 5. attn = P @ V  (B-operand Vt[b][c][s], K clamped causally)
  gemm_bt<false, false, true, false><<<dim3(C / 128, T / 128, B), 256, 0, stream>>>(
      S, Vt, attn, nullptr, 0LL, 1.f, T, C, T,
      (long long)T * T, (long long)C * T, (long long)T * C);

  // 6. out = attn Wo^T + bo  (fp32)
  gemm_bt<false, true, false, false><<<dim3(C / 128, M / 128, 1), 256, 0, stream>>>(
      attn, Wob, d_out, bws + 3 * C, 0LL, 1.f, M, C, C, 0LL, 0LL, 0LL);
}